// Round 10
// baseline (224.166 us; speedup 1.0000x reference)
//
#include <hip/hip_runtime.h>

typedef __bf16 bf16x4 __attribute__((ext_vector_type(4)));
typedef __bf16 bf16x8 __attribute__((ext_vector_type(8)));
typedef float floatx4 __attribute__((ext_vector_type(4)));

#define MFMA16(a, b, c) __builtin_amdgcn_mfma_f32_16x16x32_bf16((a), (b), (c), 0, 0, 0)

// async global->LDS, 16B per lane, dest = wave-uniform base + lane*16
#define GLD16(gptr, lptr)                                                      \
    __builtin_amdgcn_global_load_lds(                                          \
        (const __attribute__((address_space(1))) void*)(gptr),                 \
        (__attribute__((address_space(3))) void*)(lptr), 16, 0, 0)

constexpr int D_MODEL = 1024;
constexpr int SEQ = 2048;
constexpr int HEAD_DIM = 64;
constexpr int M_TOK = 2 * SEQ;   // 4096 tokens (B=2)
constexpr int N_HEADS = 16;
constexpr float ROPE_C = 0.20762050593048596f;   // log2(10000)/64

// ---------------------------------------------------------------------------
// Single-dispatch fp32 -> bf16 conversion (r10-proven) + RoPE cos/sin table
// (r16-proven).
// ---------------------------------------------------------------------------
__global__ __launch_bounds__(256) void convert_all(
    const float* __restrict__ x,  const float* __restrict__ wq,
    const float* __restrict__ wk, const float* __restrict__ wv,
    const float* __restrict__ wo, __bf16* __restrict__ dst,
    const int* __restrict__ pos, float2* __restrict__ rt)
{
    const size_t i = ((size_t)blockIdx.x * 256 + threadIdx.x) * 8;   // < 8M
    const float* s;
    size_t off;
    if (i < 4194304) { s = x; off = i; }
    else {
        const int w = (int)((i - 4194304) >> 20);
        off = (i - 4194304) & 1048575;
        s = (w == 0) ? wq : (w == 1) ? wk : (w == 2) ? wv : wo;
    }
    const floatx4 lo = *(const floatx4*)(s + off);
    const floatx4 hi = *(const floatx4*)(s + off + 4);
    bf16x8 v;
    v[0] = (__bf16)lo[0]; v[1] = (__bf16)lo[1]; v[2] = (__bf16)lo[2]; v[3] = (__bf16)lo[3];
    v[4] = (__bf16)hi[0]; v[5] = (__bf16)hi[1]; v[6] = (__bf16)hi[2]; v[7] = (__bf16)hi[3];
    *(bf16x8*)(dst + i) = v;

    // one-off RoPE table fill: first 65536 threads, one (pos, j) each
    const int gid = blockIdx.x * 256 + threadIdx.x;
    if (gid < SEQ * 32) {
        const int p = gid >> 5, j = gid & 31;
        const float ang = (float)pos[p] * exp2f(-(float)(2 * j) * ROPE_C);
        rt[gid] = make_float2(cosf(ang), sinf(ang));
    }
}

// ---------------------------------------------------------------------------
// Tiled GEMM. 128x128 tile, 4 waves, BK=32, bf16 in, unpadded 64-B LDS rows,
// 16 named floatx4 accumulators. r13 single-buffer GLD16 staging.
// r16 RoPE epilogue reads the precomputed cos/sin table (proven).
// r21 T1 XCD swizzle kept (r22 verdict: GEMM0 is compute-bound at 4% HBM,
// swizzle is time-neutral; harmless).
// MODE 0: fused QKV epilogue (N=3072); MODE 1: fp32 out projection.
// ---------------------------------------------------------------------------
template<int MODE>
__global__ __launch_bounds__(256, 2) void gemm_tiled(
    const __bf16* __restrict__ A, const __bf16* __restrict__ B,
    __bf16* __restrict__ Qb, __bf16* __restrict__ Kb, __bf16* __restrict__ Vt,
    float* __restrict__ Cf, const float2* __restrict__ rt)
{
    __shared__ __bf16 As[128 * 32];
    __shared__ __bf16 Bs[128 * 32];
    const int tid  = threadIdx.x;
    const int wave = tid >> 6, lane = tid & 63;
    const int quad = lane >> 4, l16 = lane & 15;

    constexpr int NWG = (MODE == 0) ? 32 * 24 : 32 * 8;
    const int wgid = blockIdx.x + 32 * blockIdx.y;
    const int nid  = (wgid & 7) * (NWG / 8) + (wgid >> 3);
    const int m0 = (nid & 31) * 128, n0 = (nid >> 5) * 128;
    const int wm = (wave >> 1) * 64, wn = (wave & 1) * 64;

    floatx4 c00 = {}, c01 = {}, c02 = {}, c03 = {};
    floatx4 c10 = {}, c11 = {}, c12 = {}, c13 = {};
    floatx4 c20 = {}, c21 = {}, c22 = {}, c23 = {};
    floatx4 c30 = {}, c31 = {}, c32 = {}, c33 = {};

    const int sm = tid >> 2;            // row 0..63 (this thread stages)
    const int sk = (tid & 3) * 8;       // col 0,8,16,24
    const __bf16* gA = A + (size_t)(m0 + sm) * D_MODEL + sk;
    const __bf16* gB = B + (size_t)(n0 + sm) * D_MODEL + sk;
    // wave-uniform LDS staging bases (wave w covers bytes w*1024..w*1024+1023)
    __bf16* lAs0 = &As[wave * 512];
    __bf16* lAs1 = &As[2048 + wave * 512];
    __bf16* lBs0 = &Bs[wave * 512];
    __bf16* lBs1 = &Bs[2048 + wave * 512];

    for (int k0 = 0; k0 < D_MODEL; k0 += 32) {
        __syncthreads();                // protect previous iteration LDS reads
        GLD16(gA + k0,                          lAs0);
        GLD16(gA + (size_t)64 * D_MODEL + k0,   lAs1);
        GLD16(gB + k0,                          lBs0);
        GLD16(gB + (size_t)64 * D_MODEL + k0,   lBs1);
        __syncthreads();                // compiler drains vmcnt(0) here

        const bf16x8 a0 = *(const bf16x8*)&As[(wm      + l16) * 32 + quad * 8];
        const bf16x8 a1 = *(const bf16x8*)&As[(wm + 16 + l16) * 32 + quad * 8];
        const bf16x8 a2 = *(const bf16x8*)&As[(wm + 32 + l16) * 32 + quad * 8];
        const bf16x8 a3 = *(const bf16x8*)&As[(wm + 48 + l16) * 32 + quad * 8];
        const bf16x8 b0 = *(const bf16x8*)&Bs[(wn      + l16) * 32 + quad * 8];
        const bf16x8 b1 = *(const bf16x8*)&Bs[(wn + 16 + l16) * 32 + quad * 8];
        const bf16x8 b2 = *(const bf16x8*)&Bs[(wn + 32 + l16) * 32 + quad * 8];
        const bf16x8 b3 = *(const bf16x8*)&Bs[(wn + 48 + l16) * 32 + quad * 8];

        c00 = MFMA16(a0, b0, c00); c01 = MFMA16(a0, b1, c01);
        c02 = MFMA16(a0, b2, c02); c03 = MFMA16(a0, b3, c03);
        c10 = MFMA16(a1, b0, c10); c11 = MFMA16(a1, b1, c11);
        c12 = MFMA16(a1, b2, c12); c13 = MFMA16(a1, b3, c13);
        c20 = MFMA16(a2, b0, c20); c21 = MFMA16(a2, b1, c21);
        c22 = MFMA16(a2, b2, c22); c23 = MFMA16(a2, b3, c23);
        c30 = MFMA16(a3, b0, c30); c31 = MFMA16(a3, b1, c31);
        c32 = MFMA16(a3, b2, c32); c33 = MFMA16(a3, b3, c33);
    }

#define EPI(I, J, CV) do {                                                     \
        const int n  = n0 + wn + (J) * 16 + l16;                               \
        const int t0 = m0 + wm + (I) * 16 + quad * 4;                          \
        if (MODE == 1) {                                                       \
            Cf[(size_t)(t0 + 0) * D_MODEL + n] = (CV)[0];                      \
            Cf[(size_t)(t0 + 1) * D_MODEL + n] = (CV)[1];                      \
            Cf[(size_t)(t0 + 2) * D_MODEL + n] = (CV)[2];                      \
            Cf[(size_t)(t0 + 3) * D_MODEL + n] = (CV)[3];                      \
        } else {                                                               \
            const int region = n >> 10, col = n & 1023;                        \
            if (region == 2) {                                                 \
                bf16x4 v;                                                      \
                v[0] = (__bf16)(CV)[0]; v[1] = (__bf16)(CV)[1];                \
                v[2] = (__bf16)(CV)[2]; v[3] = (__bf16)(CV)[3];                \
                const size_t vidx =                                            \
                    ((size_t)(t0 >> 11) * 1024 + col) * SEQ + (t0 & (SEQ - 1));\
                *(bf16x4*)(Vt + vidx) = v;                                     \
            } else {                                                           \
                const int d = col & (HEAD_DIM - 1);                            \
                const int j = d >> 1;                                          \
                __bf16* dst = (region == 0) ? Qb : Kb;                         \
                _Pragma("unroll")                                              \
                for (int r = 0; r < 4; ++r) {                                  \
                    float v = (CV)[r];                                         \
                    const float vp = __shfl_xor(v, 1);                         \
                    const float2 cs =                                          \
                        rt[(size_t)((t0 + r) & (SEQ - 1)) * 32 + j];           \
                    v = (d & 1) ? (vp * cs.y + v * cs.x)                       \
                                : (v * cs.x - vp * cs.y);                      \
                    dst[(size_t)(t0 + r) * D_MODEL + col] = (__bf16)v;         \
                }                                                              \
            }                                                                  \
        }                                                                      \
    } while (0)

    EPI(0, 0, c00); EPI(0, 1, c01); EPI(0, 2, c02); EPI(0, 3, c03);
    EPI(1, 0, c10); EPI(1, 1, c11); EPI(1, 2, c12); EPI(1, 3, c13);
    EPI(2, 0, c20); EPI(2, 1, c21); EPI(2, 2, c22); EPI(2, 3, c23);
    EPI(3, 0, c30); EPI(3, 1, c31); EPI(3, 2, c32); EPI(3, 3, c33);
#undef EPI
}

// ---------------------------------------------------------------------------
// Causal flash attention v10 — single-buffered r17 math + UNPAIRED grid.
// r22 evidence: 512 paired blocks = exactly 2 blocks/CU = 2 waves/SIMD;
// VALUBusy 50% == each wave issuing 25% -> no TLP to hide the serial
// softmax/staging chain. The pairing (added for balance at 2/CU) is now the
// occupancy cap. Fix: 1 tile/block, 32 tiles x 32 bh = 1024 blocks; LDS
// back to 27.6 KB (single buffer) -> 5 blocks/CU resident; TLP replaces
// the r18 dbuf ILP. Balance via LPT: longest tiles (T=31) dispatch FIRST
// (T = 31 - (slot&31)). XCD clustering kept: 4 bh per XCD, bijective
// 8 xcd x 4 bh x 32 T = 1024.
// ---------------------------------------------------------------------------
__global__ __launch_bounds__(256, 4) void attn_fused(
    const __bf16* Q, const __bf16* __restrict__ K,
    const __bf16* __restrict__ Vt, __bf16* O)
{
    const int tid  = threadIdx.x;
    const int wave = tid >> 6, lane = tid & 63;
    const int quad = lane >> 4, l16 = lane & 15;

    // XCD-clustered LPT mapping
    const int wgid = blockIdx.x + 32 * blockIdx.y;   // hw linear dispatch id
    const int xcd  = wgid & 7;
    const int slot = wgid >> 3;                      // 0..127
    const int bh   = (xcd << 2) | (slot >> 5);       // 4 heads per XCD
    const int T    = 31 - (slot & 31);               // longest-first

    const size_t base  = (size_t)(bh >> 4) * SEQ * D_MODEL + (size_t)(bh & 15) * HEAD_DIM;
    const __bf16* kbase  = K + base;
    const __bf16* vtbase = Vt + (size_t)bh * HEAD_DIM * SEQ;

    __shared__ __bf16 Ks[64][72];    // [key][dim]
    __shared__ __bf16 Vs[64][72];    // [dim][key]
    __shared__ __bf16 P[4][16][72];  // per-wave [query l16][key 0..63]

    constexpr float C2 = 0.18033688011112042f;   // 0.125 * log2(e)
    const int sr = tid >> 2;            // staging row 0..63
    const int sc = (tid & 3) * 16;      // staging col 0,16,32,48

    const int Q0  = T * 64;
    const int q0w = Q0 + wave * 16;
    const int qg  = q0w + l16;

    const __bf16* qrow = Q + base + (size_t)(q0w + l16) * D_MODEL + quad * 8;
    const bf16x8 qf0 = *(const bf16x8*)(qrow);
    const bf16x8 qf1 = *(const bf16x8*)(qrow + 32);

    float mm = -__builtin_inff(), l_i = 0.f;
    floatx4 o0 = {}, o1 = {}, o2 = {}, o3 = {};

    for (int k0 = 0; k0 <= Q0; k0 += 64) {
        __syncthreads();   // protect previous iteration LDS reads
        {
            const __bf16* kgp = kbase + (size_t)(k0 + sr) * D_MODEL + sc;
            *(bf16x8*)&Ks[sr][sc]     = *(const bf16x8*)(kgp);
            *(bf16x8*)&Ks[sr][sc + 8] = *(const bf16x8*)(kgp + 8);
            const __bf16* vgp = vtbase + (size_t)sr * SEQ + k0 + sc;
            *(bf16x8*)&Vs[sr][sc]     = *(const bf16x8*)(vgp);
            *(bf16x8*)&Vs[sr][sc + 8] = *(const bf16x8*)(vgp + 8);
        }
        __syncthreads();

        // ---- scores: S^T[64 keys][16 queries], A = K rows from LDS ----
        floatx4 s0 = {}, s1 = {}, s2 = {}, s3 = {};
        s0 = MFMA16(*(const bf16x8*)&Ks[l16][quad * 8],      qf0, s0);
        s0 = MFMA16(*(const bf16x8*)&Ks[l16][32 + quad * 8], qf1, s0);
        s1 = MFMA16(*(const bf16x8*)&Ks[16 + l16][quad * 8],      qf0, s1);
        s1 = MFMA16(*(const bf16x8*)&Ks[16 + l16][32 + quad * 8], qf1, s1);
        s2 = MFMA16(*(const bf16x8*)&Ks[32 + l16][quad * 8],      qf0, s2);
        s2 = MFMA16(*(const bf16x8*)&Ks[32 + l16][32 + quad * 8], qf1, s2);
        s3 = MFMA16(*(const bf16x8*)&Ks[48 + l16][quad * 8],      qf0, s3);
        s3 = MFMA16(*(const bf16x8*)&Ks[48 + l16][32 + quad * 8], qf1, s3);

        if (k0 == Q0) {   // single masked tail block
#pragma unroll
            for (int r = 0; r < 4; ++r) {
                const int kb = k0 + quad * 4 + r;
                if (kb      > qg) s0[r] = -__builtin_inff();
                if (kb + 16 > qg) s1[r] = -__builtin_inff();
                if (kb + 32 > qg) s2[r] = -__builtin_inff();
                if (kb + 48 > qg) s3[r] = -__builtin_inff();
            }
        }

        // ---- online softmax over 64 keys (per-lane scalar state) ----
        float mx = fmaxf(fmaxf(fmaxf(s0[0], s0[1]), fmaxf(s0[2], s0[3])),
                         fmaxf(fmaxf(s1[0], s1[1]), fmaxf(s1[2], s1[3])));
        mx = fmaxf(mx, fmaxf(fmaxf(fmaxf(s2[0], s2[1]), fmaxf(s2[2], s2[3])),
                             fmaxf(fmaxf(s3[0], s3[1]), fmaxf(s3[2], s3[3]))));
        mx = fmaxf(mx, __shfl_xor(mx, 16));
        mx = fmaxf(mx, __shfl_xor(mx, 32));
        const float mmn  = fmaxf(mm, mx * C2);
        const float alpha = exp2f(mm - mmn);
        float rs = 0.f;
#pragma unroll
        for (int r = 0; r < 4; ++r) {
            s0[r] = exp2f(s0[r] * C2 - mmn);
            s1[r] = exp2f(s1[r] * C2 - mmn);
            s2[r] = exp2f(s2[r] * C2 - mmn);
            s3[r] = exp2f(s3[r] * C2 - mmn);
            rs += s0[r] + s1[r] + s2[r] + s3[r];
        }
        rs += __shfl_xor(rs, 16);
        rs += __shfl_xor(rs, 32);
        l_i = l_i * alpha + rs;
        mm = mmn;
        o0 *= alpha; o1 *= alpha; o2 *= alpha; o3 *= alpha;

        // ---- P: C-layout -> per-wave LDS -> A-layout ----
        bf16x4 pw0, pw1, pw2, pw3;
#pragma unroll
        for (int r = 0; r < 4; ++r) {
            pw0[r] = (__bf16)s0[r]; pw1[r] = (__bf16)s1[r];
            pw2[r] = (__bf16)s2[r]; pw3[r] = (__bf16)s3[r];
        }
        *(bf16x4*)&P[wave][l16][quad * 4]      = pw0;
        *(bf16x4*)&P[wave][l16][16 + quad * 4] = pw1;
        *(bf16x4*)&P[wave][l16][32 + quad * 4] = pw2;
        *(bf16x4*)&P[wave][l16][48 + quad * 4] = pw3;
        const bf16x8 pp0 = *(const bf16x8*)&P[wave][l16][quad * 8];
        const bf16x8 pp1 = *(const bf16x8*)&P[wave][l16][32 + quad * 8];

        // ---- PV: O^T[dim][16q], A = V rows from LDS ----
        o0 = MFMA16(*(const bf16x8*)&Vs[l16][quad * 8],      pp0, o0);
        o0 = MFMA16(*(const bf16x8*)&Vs[l16][32 + quad * 8], pp1, o0);
        o1 = MFMA16(*(const bf16x8*)&Vs[16 + l16][quad * 8],      pp0, o1);
        o1 = MFMA16(*(const bf16x8*)&Vs[16 + l16][32 + quad * 8], pp1, o1);
        o2 = MFMA16(*(const bf16x8*)&Vs[32 + l16][quad * 8],      pp0, o2);
        o2 = MFMA16(*(const bf16x8*)&Vs[32 + l16][32 + quad * 8], pp1, o2);
        o3 = MFMA16(*(const bf16x8*)&Vs[48 + l16][quad * 8],      pp0, o3);
        o3 = MFMA16(*(const bf16x8*)&Vs[48 + l16][32 + quad * 8], pp1, o3);
    }

    // ---- epilogue: O[token q0w+l16][dim quad*4+r + 16g], bf16x4 ----
    const float rl = 1.0f / l_i;
    __bf16* orow = O + base + (size_t)(q0w + l16) * D_MODEL + quad * 4;
    bf16x4 w0, w1, w2, w3;
#pragma unroll
    for (int r = 0; r < 4; ++r) {
        w0[r] = (__bf16)(o0[r] * rl);
        w1[r] = (__bf16)(o1[r] * rl);
        w2[r] = (__bf16)(o2[r] * rl);
        w3[r] = (__bf16)(o3[r] * rl);
    }
    *(bf16x4*)(orow)      = w0;
    *(bf16x4*)(orow + 16) = w1;
    *(bf16x4*)(orow + 32) = w2;
    *(bf16x4*)(orow + 48) = w3;
}

// ---------------------------------------------------------------------------
// ws layout (40 MB): Xb 8 | Wb (Wq,Wk,Wv,Wo cat) 8 | Qb 8 | Kb 8 | Vt 8.
// RoPE table (512 KB) lives in d_out: written by convert_all, read by
// gemm_tiled<0>, dead by the time gemm_tiled<1> overwrites d_out.
// Attention output in-place over Qb. Inputs fp32, output fp32.
// ---------------------------------------------------------------------------
extern "C" void kernel_launch(void* const* d_in, const int* in_sizes, int n_in,
                              void* d_out, int out_size, void* d_ws, size_t ws_size,
                              hipStream_t stream) {
    const int* pos = (const int*)d_in[1];
    float* out = (float*)d_out;

    const size_t xe = (size_t)M_TOK * D_MODEL;      // 4M elements
    const size_t we = (size_t)D_MODEL * D_MODEL;    // 1M elements
    __bf16* Xb = (__bf16*)d_ws;
    __bf16* Wb = Xb + xe;          // [Wq | Wk | Wv | Wo]
    __bf16* Qb = Wb + 4 * we;
    __bf16* Kb = Qb + xe;
    __bf16* Vt = Kb + xe;          // [b*16+h][64][2048] transposed V
    float2* rt = (float2*)d_out;   // RoPE table, scratch use of out buffer

    convert_all<<<4096, 256, 0, stream>>>(
        (const float*)d_in[0], (const float*)d_in[2], (const float*)d_in[3],
        (const float*)d_in[4], (const float*)d_in[5], Xb, pos, rt);

    gemm_tiled<0><<<dim3(M_TOK / 128, 3072 / 128), 256, 0, stream>>>(
        Xb, Wb, Qb, Kb, Vt, nullptr, rt);

    // unpaired LPT grid: 32 tiles x 32 bh = 1024 blocks, ~5 resident/CU
    attn_fused<<<dim3(32, 32), 256, 0, stream>>>(Qb, Kb, Vt, Qb);

    gemm_tiled<1><<<dim3(M_TOK / 128, D_MODEL / 128), 256, 0, stream>>>(
        Qb, Wb + 3 * we, nullptr, nullptr, nullptr, out, rt);
}

// Round 11
// 191.733 us; speedup vs baseline: 1.1692x; 1.1692x over previous
//
#include <hip/hip_runtime.h>

typedef __bf16 bf16x4 __attribute__((ext_vector_type(4)));
typedef __bf16 bf16x8 __attribute__((ext_vector_type(8)));
typedef float floatx4 __attribute__((ext_vector_type(4)));

#define MFMA16(a, b, c) __builtin_amdgcn_mfma_f32_16x16x32_bf16((a), (b), (c), 0, 0, 0)

// async global->LDS, 16B per lane, dest = wave-uniform base + lane*16
#define GLD16(gptr, lptr)                                                      \
    __builtin_amdgcn_global_load_lds(                                          \
        (const __attribute__((address_space(1))) void*)(gptr),                 \
        (__attribute__((address_space(3))) void*)(lptr), 16, 0, 0)

constexpr int D_MODEL = 1024;
constexpr int SEQ = 2048;
constexpr int HEAD_DIM = 64;
constexpr int M_TOK = 2 * SEQ;   // 4096 tokens (B=2)
constexpr int N_HEADS = 16;
constexpr float ROPE_C = 0.20762050593048596f;   // log2(10000)/64

// ---------------------------------------------------------------------------
// Single-dispatch fp32 -> bf16 conversion (r10-proven) + RoPE cos/sin table
// (r16-proven).
// ---------------------------------------------------------------------------
__global__ __launch_bounds__(256) void convert_all(
    const float* __restrict__ x,  const float* __restrict__ wq,
    const float* __restrict__ wk, const float* __restrict__ wv,
    const float* __restrict__ wo, __bf16* __restrict__ dst,
    const int* __restrict__ pos, float2* __restrict__ rt)
{
    const size_t i = ((size_t)blockIdx.x * 256 + threadIdx.x) * 8;   // < 8M
    const float* s;
    size_t off;
    if (i < 4194304) { s = x; off = i; }
    else {
        const int w = (int)((i - 4194304) >> 20);
        off = (i - 4194304) & 1048575;
        s = (w == 0) ? wq : (w == 1) ? wk : (w == 2) ? wv : wo;
    }
    const floatx4 lo = *(const floatx4*)(s + off);
    const floatx4 hi = *(const floatx4*)(s + off + 4);
    bf16x8 v;
    v[0] = (__bf16)lo[0]; v[1] = (__bf16)lo[1]; v[2] = (__bf16)lo[2]; v[3] = (__bf16)lo[3];
    v[4] = (__bf16)hi[0]; v[5] = (__bf16)hi[1]; v[6] = (__bf16)hi[2]; v[7] = (__bf16)hi[3];
    *(bf16x8*)(dst + i) = v;

    // one-off RoPE table fill: first 65536 threads, one (pos, j) each
    const int gid = blockIdx.x * 256 + threadIdx.x;
    if (gid < SEQ * 32) {
        const int p = gid >> 5, j = gid & 31;
        const float ang = (float)pos[p] * exp2f(-(float)(2 * j) * ROPE_C);
        rt[gid] = make_float2(cosf(ang), sinf(ang));
    }
}

// ---------------------------------------------------------------------------
// Tiled GEMM. 128x128 tile, 4 waves, BK=32, bf16 in, unpadded 64-B LDS rows,
// 16 named floatx4 accumulators. r13 single-buffer GLD16 staging.
// r16 RoPE epilogue (proven). r21 T1 XCD swizzle kept (time-neutral).
// MODE 0: fused QKV epilogue (N=3072); MODE 1: fp32 out projection.
// ---------------------------------------------------------------------------
template<int MODE>
__global__ __launch_bounds__(256, 2) void gemm_tiled(
    const __bf16* __restrict__ A, const __bf16* __restrict__ B,
    __bf16* __restrict__ Qb, __bf16* __restrict__ Kb, __bf16* __restrict__ Vt,
    float* __restrict__ Cf, const float2* __restrict__ rt)
{
    __shared__ __bf16 As[128 * 32];
    __shared__ __bf16 Bs[128 * 32];
    const int tid  = threadIdx.x;
    const int wave = tid >> 6, lane = tid & 63;
    const int quad = lane >> 4, l16 = lane & 15;

    constexpr int NWG = (MODE == 0) ? 32 * 24 : 32 * 8;
    const int wgid = blockIdx.x + 32 * blockIdx.y;
    const int nid  = (wgid & 7) * (NWG / 8) + (wgid >> 3);
    const int m0 = (nid & 31) * 128, n0 = (nid >> 5) * 128;
    const int wm = (wave >> 1) * 64, wn = (wave & 1) * 64;

    floatx4 c00 = {}, c01 = {}, c02 = {}, c03 = {};
    floatx4 c10 = {}, c11 = {}, c12 = {}, c13 = {};
    floatx4 c20 = {}, c21 = {}, c22 = {}, c23 = {};
    floatx4 c30 = {}, c31 = {}, c32 = {}, c33 = {};

    const int sm = tid >> 2;            // row 0..63 (this thread stages)
    const int sk = (tid & 3) * 8;       // col 0,8,16,24
    const __bf16* gA = A + (size_t)(m0 + sm) * D_MODEL + sk;
    const __bf16* gB = B + (size_t)(n0 + sm) * D_MODEL + sk;
    // wave-uniform LDS staging bases (wave w covers bytes w*1024..w*1024+1023)
    __bf16* lAs0 = &As[wave * 512];
    __bf16* lAs1 = &As[2048 + wave * 512];
    __bf16* lBs0 = &Bs[wave * 512];
    __bf16* lBs1 = &Bs[2048 + wave * 512];

    for (int k0 = 0; k0 < D_MODEL; k0 += 32) {
        __syncthreads();                // protect previous iteration LDS reads
        GLD16(gA + k0,                          lAs0);
        GLD16(gA + (size_t)64 * D_MODEL + k0,   lAs1);
        GLD16(gB + k0,                          lBs0);
        GLD16(gB + (size_t)64 * D_MODEL + k0,   lBs1);
        __syncthreads();                // compiler drains vmcnt(0) here

        const bf16x8 a0 = *(const bf16x8*)&As[(wm      + l16) * 32 + quad * 8];
        const bf16x8 a1 = *(const bf16x8*)&As[(wm + 16 + l16) * 32 + quad * 8];
        const bf16x8 a2 = *(const bf16x8*)&As[(wm + 32 + l16) * 32 + quad * 8];
        const bf16x8 a3 = *(const bf16x8*)&As[(wm + 48 + l16) * 32 + quad * 8];
        const bf16x8 b0 = *(const bf16x8*)&Bs[(wn      + l16) * 32 + quad * 8];
        const bf16x8 b1 = *(const bf16x8*)&Bs[(wn + 16 + l16) * 32 + quad * 8];
        const bf16x8 b2 = *(const bf16x8*)&Bs[(wn + 32 + l16) * 32 + quad * 8];
        const bf16x8 b3 = *(const bf16x8*)&Bs[(wn + 48 + l16) * 32 + quad * 8];

        c00 = MFMA16(a0, b0, c00); c01 = MFMA16(a0, b1, c01);
        c02 = MFMA16(a0, b2, c02); c03 = MFMA16(a0, b3, c03);
        c10 = MFMA16(a1, b0, c10); c11 = MFMA16(a1, b1, c11);
        c12 = MFMA16(a1, b2, c12); c13 = MFMA16(a1, b3, c13);
        c20 = MFMA16(a2, b0, c20); c21 = MFMA16(a2, b1, c21);
        c22 = MFMA16(a2, b2, c22); c23 = MFMA16(a2, b3, c23);
        c30 = MFMA16(a3, b0, c30); c31 = MFMA16(a3, b1, c31);
        c32 = MFMA16(a3, b2, c32); c33 = MFMA16(a3, b3, c33);
    }

#define EPI(I, J, CV) do {                                                     \
        const int n  = n0 + wn + (J) * 16 + l16;                               \
        const int t0 = m0 + wm + (I) * 16 + quad * 4;                          \
        if (MODE == 1) {                                                       \
            Cf[(size_t)(t0 + 0) * D_MODEL + n] = (CV)[0];                      \
            Cf[(size_t)(t0 + 1) * D_MODEL + n] = (CV)[1];                      \
            Cf[(size_t)(t0 + 2) * D_MODEL + n] = (CV)[2];                      \
            Cf[(size_t)(t0 + 3) * D_MODEL + n] = (CV)[3];                      \
        } else {                                                               \
            const int region = n >> 10, col = n & 1023;                        \
            if (region == 2) {                                                 \
                bf16x4 v;                                                      \
                v[0] = (__bf16)(CV)[0]; v[1] = (__bf16)(CV)[1];                \
                v[2] = (__bf16)(CV)[2]; v[3] = (__bf16)(CV)[3];                \
                const size_t vidx =                                            \
                    ((size_t)(t0 >> 11) * 1024 + col) * SEQ + (t0 & (SEQ - 1));\
                *(bf16x4*)(Vt + vidx) = v;                                     \
            } else {                                                           \
                const int d = col & (HEAD_DIM - 1);                            \
                const int j = d >> 1;                                          \
                __bf16* dst = (region == 0) ? Qb : Kb;                         \
                _Pragma("unroll")                                              \
                for (int r = 0; r < 4; ++r) {                                  \
                    float v = (CV)[r];                                         \
                    const float vp = __shfl_xor(v, 1);                         \
                    const float2 cs =                                          \
                        rt[(size_t)((t0 + r) & (SEQ - 1)) * 32 + j];           \
                    v = (d & 1) ? (vp * cs.y + v * cs.x)                       \
                                : (v * cs.x - vp * cs.y);                      \
                    dst[(size_t)(t0 + r) * D_MODEL + col] = (__bf16)v;         \
                }                                                              \
            }                                                                  \
        }                                                                      \
    } while (0)

    EPI(0, 0, c00); EPI(0, 1, c01); EPI(0, 2, c02); EPI(0, 3, c03);
    EPI(1, 0, c10); EPI(1, 1, c11); EPI(1, 2, c12); EPI(1, 3, c13);
    EPI(2, 0, c20); EPI(2, 1, c21); EPI(2, 2, c22); EPI(2, 3, c23);
    EPI(3, 0, c30); EPI(3, 1, c31); EPI(3, 2, c32); EPI(3, 3, c33);
#undef EPI
}

// ---------------------------------------------------------------------------
// Causal flash attention v11 — r18 compute (dbuf + T14, PROVEN 62us) on an
// UNPAIRED grid with GLOBAL LPT. r23 diagnosis: (1) dropping dbuf+T14
// restored the naked staging chain; (2) per-bh LPT dispatched fresh T=31
// blocks 3/4 into the kernel -> 40us single-block tail -> occupancy stuck
// at 18%, VALUBusy 27% < balanced-work prediction 38% (CUs idle).
// Fix: slot>>2 -> T (all four T=31 blocks per XCD dispatch FIRST), slot&3
// -> bh. Bijective: 8 xcd x 4 bh x 32 T = 1024 blocks. LDS 46 KB -> 3
// blocks/CU resident (was 2): TLP on top of dbuf ILP, short tail.
// ---------------------------------------------------------------------------
__global__ __launch_bounds__(256, 4) void attn_fused(
    const __bf16* Q, const __bf16* __restrict__ K,
    const __bf16* __restrict__ Vt, __bf16* O)
{
    const int tid  = threadIdx.x;
    const int wave = tid >> 6, lane = tid & 63;
    const int quad = lane >> 4, l16 = lane & 15;

    // XCD-clustered GLOBAL-LPT mapping
    const int wgid = blockIdx.x + 32 * blockIdx.y;   // hw linear dispatch id
    const int xcd  = wgid & 7;
    const int slot = wgid >> 3;                      // 0..127
    const int bh   = (xcd << 2) | (slot & 3);        // 4 heads per XCD
    const int T    = 31 - (slot >> 2);               // longest first, global

    const size_t base  = (size_t)(bh >> 4) * SEQ * D_MODEL + (size_t)(bh & 15) * HEAD_DIM;
    const __bf16* kbase  = K + base;
    const __bf16* vtbase = Vt + (size_t)bh * HEAD_DIM * SEQ;

    __shared__ __bf16 Ks[2][64][72];    // [buf][key][dim]
    __shared__ __bf16 Vs[2][64][72];    // [buf][dim][key]
    __shared__ __bf16 P[4][16][72];     // per-wave [query l16][key 0..63]

    constexpr float C2 = 0.18033688011112042f;   // 0.125 * log2(e)
    const int sr = tid >> 2;            // staging row 0..63
    const int sc = (tid & 3) * 16;      // staging col 0,16,32,48

    const int Q0  = T * 64;
    const int q0w = Q0 + wave * 16;
    const int qg  = q0w + l16;

    const __bf16* qrow = Q + base + (size_t)(q0w + l16) * D_MODEL + quad * 8;
    const bf16x8 qf0 = *(const bf16x8*)(qrow);
    const bf16x8 qf1 = *(const bf16x8*)(qrow + 32);

    float mm = -__builtin_inff(), l_i = 0.f;
    floatx4 o0 = {}, o1 = {}, o2 = {}, o3 = {};

    // ---- prologue: tile 0 -> regs -> buf0 ----
    bf16x8 kr0, kr1, vr0, vr1;
    {
        const __bf16* kgp = kbase + (size_t)sr * D_MODEL + sc;
        kr0 = *(const bf16x8*)(kgp);
        kr1 = *(const bf16x8*)(kgp + 8);
        const __bf16* vgp = vtbase + (size_t)sr * SEQ + sc;
        vr0 = *(const bf16x8*)(vgp);
        vr1 = *(const bf16x8*)(vgp + 8);
    }
    __syncthreads();
    *(bf16x8*)&Ks[0][sr][sc]     = kr0;
    *(bf16x8*)&Ks[0][sr][sc + 8] = kr1;
    *(bf16x8*)&Vs[0][sr][sc]     = vr0;
    *(bf16x8*)&Vs[0][sr][sc + 8] = vr1;
    int cur = 0;

    for (int k0 = 0; k0 <= Q0; k0 += 64) {
        const bool pf = (k0 + 64 <= Q0);
        if (pf) {   // T14 issue-early: next-tile loads into regs
            const __bf16* kgp = kbase + (size_t)(k0 + 64 + sr) * D_MODEL + sc;
            kr0 = *(const bf16x8*)(kgp);
            kr1 = *(const bf16x8*)(kgp + 8);
            const __bf16* vgp = vtbase + (size_t)sr * SEQ + (k0 + 64) + sc;
            vr0 = *(const bf16x8*)(vgp);
            vr1 = *(const bf16x8*)(vgp + 8);
        }
        __syncthreads();   // buf[cur] writes visible; prev reads done

        // ---- scores: S^T[64 keys][16 queries], A = K rows from LDS ----
        floatx4 s0 = {}, s1 = {}, s2 = {}, s3 = {};
        s0 = MFMA16(*(const bf16x8*)&Ks[cur][l16][quad * 8],      qf0, s0);
        s0 = MFMA16(*(const bf16x8*)&Ks[cur][l16][32 + quad * 8], qf1, s0);
        s1 = MFMA16(*(const bf16x8*)&Ks[cur][16 + l16][quad * 8],      qf0, s1);
        s1 = MFMA16(*(const bf16x8*)&Ks[cur][16 + l16][32 + quad * 8], qf1, s1);
        s2 = MFMA16(*(const bf16x8*)&Ks[cur][32 + l16][quad * 8],      qf0, s2);
        s2 = MFMA16(*(const bf16x8*)&Ks[cur][32 + l16][32 + quad * 8], qf1, s2);
        s3 = MFMA16(*(const bf16x8*)&Ks[cur][48 + l16][quad * 8],      qf0, s3);
        s3 = MFMA16(*(const bf16x8*)&Ks[cur][48 + l16][32 + quad * 8], qf1, s3);

        if (k0 == Q0) {   // single masked tail block
#pragma unroll
            for (int r = 0; r < 4; ++r) {
                const int kb = k0 + quad * 4 + r;
                if (kb      > qg) s0[r] = -__builtin_inff();
                if (kb + 16 > qg) s1[r] = -__builtin_inff();
                if (kb + 32 > qg) s2[r] = -__builtin_inff();
                if (kb + 48 > qg) s3[r] = -__builtin_inff();
            }
        }

        // ---- online softmax over 64 keys (per-lane scalar state) ----
        float mx = fmaxf(fmaxf(fmaxf(s0[0], s0[1]), fmaxf(s0[2], s0[3])),
                         fmaxf(fmaxf(s1[0], s1[1]), fmaxf(s1[2], s1[3])));
        mx = fmaxf(mx, fmaxf(fmaxf(fmaxf(s2[0], s2[1]), fmaxf(s2[2], s2[3])),
                             fmaxf(fmaxf(s3[0], s3[1]), fmaxf(s3[2], s3[3]))));
        mx = fmaxf(mx, __shfl_xor(mx, 16));
        mx = fmaxf(mx, __shfl_xor(mx, 32));
        const float mmn  = fmaxf(mm, mx * C2);
        const float alpha = exp2f(mm - mmn);
        float rs = 0.f;
#pragma unroll
        for (int r = 0; r < 4; ++r) {
            s0[r] = exp2f(s0[r] * C2 - mmn);
            s1[r] = exp2f(s1[r] * C2 - mmn);
            s2[r] = exp2f(s2[r] * C2 - mmn);
            s3[r] = exp2f(s3[r] * C2 - mmn);
            rs += s0[r] + s1[r] + s2[r] + s3[r];
        }
        rs += __shfl_xor(rs, 16);
        rs += __shfl_xor(rs, 32);
        l_i = l_i * alpha + rs;
        mm = mmn;
        o0 *= alpha; o1 *= alpha; o2 *= alpha; o3 *= alpha;

        // ---- write-late staging: regs -> buf[cur^1] (no reader now) ----
        if (pf) {
            *(bf16x8*)&Ks[cur ^ 1][sr][sc]     = kr0;
            *(bf16x8*)&Ks[cur ^ 1][sr][sc + 8] = kr1;
            *(bf16x8*)&Vs[cur ^ 1][sr][sc]     = vr0;
            *(bf16x8*)&Vs[cur ^ 1][sr][sc + 8] = vr1;
        }

        // ---- P: C-layout -> per-wave LDS -> A-layout ----
        bf16x4 pw0, pw1, pw2, pw3;
#pragma unroll
        for (int r = 0; r < 4; ++r) {
            pw0[r] = (__bf16)s0[r]; pw1[r] = (__bf16)s1[r];
            pw2[r] = (__bf16)s2[r]; pw3[r] = (__bf16)s3[r];
        }
        *(bf16x4*)&P[wave][l16][quad * 4]      = pw0;
        *(bf16x4*)&P[wave][l16][16 + quad * 4] = pw1;
        *(bf16x4*)&P[wave][l16][32 + quad * 4] = pw2;
        *(bf16x4*)&P[wave][l16][48 + quad * 4] = pw3;
        const bf16x8 pp0 = *(const bf16x8*)&P[wave][l16][quad * 8];
        const bf16x8 pp1 = *(const bf16x8*)&P[wave][l16][32 + quad * 8];

        // ---- PV: O^T[dim][16q], A = V rows from LDS ----
        o0 = MFMA16(*(const bf16x8*)&Vs[cur][l16][quad * 8],      pp0, o0);
        o0 = MFMA16(*(const bf16x8*)&Vs[cur][l16][32 + quad * 8], pp1, o0);
        o1 = MFMA16(*(const bf16x8*)&Vs[cur][16 + l16][quad * 8],      pp0, o1);
        o1 = MFMA16(*(const bf16x8*)&Vs[cur][16 + l16][32 + quad * 8], pp1, o1);
        o2 = MFMA16(*(const bf16x8*)&Vs[cur][32 + l16][quad * 8],      pp0, o2);
        o2 = MFMA16(*(const bf16x8*)&Vs[cur][32 + l16][32 + quad * 8], pp1, o2);
        o3 = MFMA16(*(const bf16x8*)&Vs[cur][48 + l16][quad * 8],      pp0, o3);
        o3 = MFMA16(*(const bf16x8*)&Vs[cur][48 + l16][32 + quad * 8], pp1, o3);
        cur ^= 1;
    }

    // ---- epilogue: O[token q0w+l16][dim quad*4+r + 16g], bf16x4 ----
    const float rl = 1.0f / l_i;
    __bf16* orow = O + base + (size_t)(q0w + l16) * D_MODEL + quad * 4;
    bf16x4 w0, w1, w2, w3;
#pragma unroll
    for (int r = 0; r < 4; ++r) {
        w0[r] = (__bf16)(o0[r] * rl);
        w1[r] = (__bf16)(o1[r] * rl);
        w2[r] = (__bf16)(o2[r] * rl);
        w3[r] = (__bf16)(o3[r] * rl);
    }
    *(bf16x4*)(orow)      = w0;
    *(bf16x4*)(orow + 16) = w1;
    *(bf16x4*)(orow + 32) = w2;
    *(bf16x4*)(orow + 48) = w3;
}

// ---------------------------------------------------------------------------
// ws layout (40 MB): Xb 8 | Wb (Wq,Wk,Wv,Wo cat) 8 | Qb 8 | Kb 8 | Vt 8.
// RoPE table (512 KB) lives in d_out: written by convert_all, read by
// gemm_tiled<0>, dead by the time gemm_tiled<1> overwrites d_out.
// Attention output in-place over Qb. Inputs fp32, output fp32.
// ---------------------------------------------------------------------------
extern "C" void kernel_launch(void* const* d_in, const int* in_sizes, int n_in,
                              void* d_out, int out_size, void* d_ws, size_t ws_size,
                              hipStream_t stream) {
    const int* pos = (const int*)d_in[1];
    float* out = (float*)d_out;

    const size_t xe = (size_t)M_TOK * D_MODEL;      // 4M elements
    const size_t we = (size_t)D_MODEL * D_MODEL;    // 1M elements
    __bf16* Xb = (__bf16*)d_ws;
    __bf16* Wb = Xb + xe;          // [Wq | Wk | Wv | Wo]
    __bf16* Qb = Wb + 4 * we;
    __bf16* Kb = Qb + xe;
    __bf16* Vt = Kb + xe;          // [b*16+h][64][2048] transposed V
    float2* rt = (float2*)d_out;   // RoPE table, scratch use of out buffer

    convert_all<<<4096, 256, 0, stream>>>(
        (const float*)d_in[0], (const float*)d_in[2], (const float*)d_in[3],
        (const float*)d_in[4], (const float*)d_in[5], Xb, pos, rt);

    gemm_tiled<0><<<dim3(M_TOK / 128, 3072 / 128), 256, 0, stream>>>(
        Xb, Wb, Qb, Kb, Vt, nullptr, rt);

    // unpaired, XCD-clustered GLOBAL-LPT grid: 1024 blocks, 3 resident/CU
    attn_fused<<<dim3(32, 32), 256, 0, stream>>>(Qb, Kb, Vt, Qb);

    gemm_tiled<1><<<dim3(M_TOK / 128, D_MODEL / 128), 256, 0, stream>>>(
        Qb, Wb + 3 * we, nullptr, nullptr, nullptr, out, rt);
}

// Round 12
// 189.189 us; speedup vs baseline: 1.1849x; 1.0134x over previous
//
#include <hip/hip_runtime.h>

typedef __bf16 bf16x4 __attribute__((ext_vector_type(4)));
typedef __bf16 bf16x8 __attribute__((ext_vector_type(8)));
typedef float floatx4 __attribute__((ext_vector_type(4)));

#define MFMA16(a, b, c) __builtin_amdgcn_mfma_f32_16x16x32_bf16((a), (b), (c), 0, 0, 0)

// async global->LDS, 16B per lane, dest = wave-uniform base + lane*16
#define GLD16(gptr, lptr)                                                      \
    __builtin_amdgcn_global_load_lds(                                          \
        (const __attribute__((address_space(1))) void*)(gptr),                 \
        (__attribute__((address_space(3))) void*)(lptr), 16, 0, 0)

constexpr int D_MODEL = 1024;
constexpr int SEQ = 2048;
constexpr int HEAD_DIM = 64;
constexpr int M_TOK = 2 * SEQ;   // 4096 tokens (B=2)
constexpr int N_HEADS = 16;
constexpr float ROPE_C = 0.20762050593048596f;   // log2(10000)/64

// ---------------------------------------------------------------------------
// Single-dispatch fp32 -> bf16 conversion (r10-proven) + RoPE cos/sin table
// (r16-proven).
// ---------------------------------------------------------------------------
__global__ __launch_bounds__(256) void convert_all(
    const float* __restrict__ x,  const float* __restrict__ wq,
    const float* __restrict__ wk, const float* __restrict__ wv,
    const float* __restrict__ wo, __bf16* __restrict__ dst,
    const int* __restrict__ pos, float2* __restrict__ rt)
{
    const size_t i = ((size_t)blockIdx.x * 256 + threadIdx.x) * 8;   // < 8M
    const float* s;
    size_t off;
    if (i < 4194304) { s = x; off = i; }
    else {
        const int w = (int)((i - 4194304) >> 20);
        off = (i - 4194304) & 1048575;
        s = (w == 0) ? wq : (w == 1) ? wk : (w == 2) ? wv : wo;
    }
    const floatx4 lo = *(const floatx4*)(s + off);
    const floatx4 hi = *(const floatx4*)(s + off + 4);
    bf16x8 v;
    v[0] = (__bf16)lo[0]; v[1] = (__bf16)lo[1]; v[2] = (__bf16)lo[2]; v[3] = (__bf16)lo[3];
    v[4] = (__bf16)hi[0]; v[5] = (__bf16)hi[1]; v[6] = (__bf16)hi[2]; v[7] = (__bf16)hi[3];
    *(bf16x8*)(dst + i) = v;

    // one-off RoPE table fill: first 65536 threads, one (pos, j) each
    const int gid = blockIdx.x * 256 + threadIdx.x;
    if (gid < SEQ * 32) {
        const int p = gid >> 5, j = gid & 31;
        const float ang = (float)pos[p] * exp2f(-(float)(2 * j) * ROPE_C);
        rt[gid] = make_float2(cosf(ang), sinf(ang));
    }
}

// ---------------------------------------------------------------------------
// Tiled GEMM. 128x128 tile, 4 waves, BK=32, bf16 in, unpadded 64-B LDS rows,
// 16 named floatx4 accumulators. r13 single-buffer GLD16 staging.
// r16 RoPE epilogue (proven). r21 T1 XCD swizzle kept (time-neutral).
// MODE 0: fused QKV epilogue (N=3072); MODE 1: fp32 out projection.
// ---------------------------------------------------------------------------
template<int MODE>
__global__ __launch_bounds__(256, 2) void gemm_tiled(
    const __bf16* __restrict__ A, const __bf16* __restrict__ B,
    __bf16* __restrict__ Qb, __bf16* __restrict__ Kb, __bf16* __restrict__ Vt,
    float* __restrict__ Cf, const float2* __restrict__ rt)
{
    __shared__ __bf16 As[128 * 32];
    __shared__ __bf16 Bs[128 * 32];
    const int tid  = threadIdx.x;
    const int wave = tid >> 6, lane = tid & 63;
    const int quad = lane >> 4, l16 = lane & 15;

    constexpr int NWG = (MODE == 0) ? 32 * 24 : 32 * 8;
    const int wgid = blockIdx.x + 32 * blockIdx.y;
    const int nid  = (wgid & 7) * (NWG / 8) + (wgid >> 3);
    const int m0 = (nid & 31) * 128, n0 = (nid >> 5) * 128;
    const int wm = (wave >> 1) * 64, wn = (wave & 1) * 64;

    floatx4 c00 = {}, c01 = {}, c02 = {}, c03 = {};
    floatx4 c10 = {}, c11 = {}, c12 = {}, c13 = {};
    floatx4 c20 = {}, c21 = {}, c22 = {}, c23 = {};
    floatx4 c30 = {}, c31 = {}, c32 = {}, c33 = {};

    const int sm = tid >> 2;            // row 0..63 (this thread stages)
    const int sk = (tid & 3) * 8;       // col 0,8,16,24
    const __bf16* gA = A + (size_t)(m0 + sm) * D_MODEL + sk;
    const __bf16* gB = B + (size_t)(n0 + sm) * D_MODEL + sk;
    // wave-uniform LDS staging bases (wave w covers bytes w*1024..w*1024+1023)
    __bf16* lAs0 = &As[wave * 512];
    __bf16* lAs1 = &As[2048 + wave * 512];
    __bf16* lBs0 = &Bs[wave * 512];
    __bf16* lBs1 = &Bs[2048 + wave * 512];

    for (int k0 = 0; k0 < D_MODEL; k0 += 32) {
        __syncthreads();                // protect previous iteration LDS reads
        GLD16(gA + k0,                          lAs0);
        GLD16(gA + (size_t)64 * D_MODEL + k0,   lAs1);
        GLD16(gB + k0,                          lBs0);
        GLD16(gB + (size_t)64 * D_MODEL + k0,   lBs1);
        __syncthreads();                // compiler drains vmcnt(0) here

        const bf16x8 a0 = *(const bf16x8*)&As[(wm      + l16) * 32 + quad * 8];
        const bf16x8 a1 = *(const bf16x8*)&As[(wm + 16 + l16) * 32 + quad * 8];
        const bf16x8 a2 = *(const bf16x8*)&As[(wm + 32 + l16) * 32 + quad * 8];
        const bf16x8 a3 = *(const bf16x8*)&As[(wm + 48 + l16) * 32 + quad * 8];
        const bf16x8 b0 = *(const bf16x8*)&Bs[(wn      + l16) * 32 + quad * 8];
        const bf16x8 b1 = *(const bf16x8*)&Bs[(wn + 16 + l16) * 32 + quad * 8];
        const bf16x8 b2 = *(const bf16x8*)&Bs[(wn + 32 + l16) * 32 + quad * 8];
        const bf16x8 b3 = *(const bf16x8*)&Bs[(wn + 48 + l16) * 32 + quad * 8];

        c00 = MFMA16(a0, b0, c00); c01 = MFMA16(a0, b1, c01);
        c02 = MFMA16(a0, b2, c02); c03 = MFMA16(a0, b3, c03);
        c10 = MFMA16(a1, b0, c10); c11 = MFMA16(a1, b1, c11);
        c12 = MFMA16(a1, b2, c12); c13 = MFMA16(a1, b3, c13);
        c20 = MFMA16(a2, b0, c20); c21 = MFMA16(a2, b1, c21);
        c22 = MFMA16(a2, b2, c22); c23 = MFMA16(a2, b3, c23);
        c30 = MFMA16(a3, b0, c30); c31 = MFMA16(a3, b1, c31);
        c32 = MFMA16(a3, b2, c32); c33 = MFMA16(a3, b3, c33);
    }

#define EPI(I, J, CV) do {                                                     \
        const int n  = n0 + wn + (J) * 16 + l16;                               \
        const int t0 = m0 + wm + (I) * 16 + quad * 4;                          \
        if (MODE == 1) {                                                       \
            Cf[(size_t)(t0 + 0) * D_MODEL + n] = (CV)[0];                      \
            Cf[(size_t)(t0 + 1) * D_MODEL + n] = (CV)[1];                      \
            Cf[(size_t)(t0 + 2) * D_MODEL + n] = (CV)[2];                      \
            Cf[(size_t)(t0 + 3) * D_MODEL + n] = (CV)[3];                      \
        } else {                                                               \
            const int region = n >> 10, col = n & 1023;                        \
            if (region == 2) {                                                 \
                bf16x4 v;                                                      \
                v[0] = (__bf16)(CV)[0]; v[1] = (__bf16)(CV)[1];                \
                v[2] = (__bf16)(CV)[2]; v[3] = (__bf16)(CV)[3];                \
                const size_t vidx =                                            \
                    ((size_t)(t0 >> 11) * 1024 + col) * SEQ + (t0 & (SEQ - 1));\
                *(bf16x4*)(Vt + vidx) = v;                                     \
            } else {                                                           \
                const int d = col & (HEAD_DIM - 1);                            \
                const int j = d >> 1;                                          \
                __bf16* dst = (region == 0) ? Qb : Kb;                         \
                _Pragma("unroll")                                              \
                for (int r = 0; r < 4; ++r) {                                  \
                    float v = (CV)[r];                                         \
                    const float vp = __shfl_xor(v, 1);                         \
                    const float2 cs =                                          \
                        rt[(size_t)((t0 + r) & (SEQ - 1)) * 32 + j];           \
                    v = (d & 1) ? (vp * cs.y + v * cs.x)                       \
                                : (v * cs.x - vp * cs.y);                      \
                    dst[(size_t)(t0 + r) * D_MODEL + col] = (__bf16)v;         \
                }                                                              \
            }                                                                  \
        }                                                                      \
    } while (0)

    EPI(0, 0, c00); EPI(0, 1, c01); EPI(0, 2, c02); EPI(0, 3, c03);
    EPI(1, 0, c10); EPI(1, 1, c11); EPI(1, 2, c12); EPI(1, 3, c13);
    EPI(2, 0, c20); EPI(2, 1, c21); EPI(2, 2, c22); EPI(2, 3, c23);
    EPI(3, 0, c30); EPI(3, 1, c31); EPI(3, 2, c32); EPI(3, 3, c33);
#undef EPI
}

// ---------------------------------------------------------------------------
// Causal flash attention v12 — v11 (r24: global-LPT unpaired grid, dbuf +
// T14, 54us, occ 25%) + VALU cuts. r24 evidence: VALU 57% + MFMA 13% +
// DS-issue => SIMD issue slots near-saturated, VALU-dominated. Cuts:
// (1) T13 defer-max THR=8: skip mm update + o/l rescale (~18 VALU/iter)
//     when __all(mx*C2 - mm <= 8); P bounded by 2^8 (bf16-safe, HK-proven).
//     First iter (mm=-inf) takes the branch, alpha=0 -> correct init.
// (2) max3-shaped reduction (15 fmax -> 8 v_max3, depth 3).
// (3) T5 s_setprio(1) around MFMA clusters (attn-proven +4-7%, m191).
// ---------------------------------------------------------------------------
__global__ __launch_bounds__(256, 4) void attn_fused(
    const __bf16* Q, const __bf16* __restrict__ K,
    const __bf16* __restrict__ Vt, __bf16* O)
{
    const int tid  = threadIdx.x;
    const int wave = tid >> 6, lane = tid & 63;
    const int quad = lane >> 4, l16 = lane & 15;

    // XCD-clustered GLOBAL-LPT mapping (r24-proven)
    const int wgid = blockIdx.x + 32 * blockIdx.y;   // hw linear dispatch id
    const int xcd  = wgid & 7;
    const int slot = wgid >> 3;                      // 0..127
    const int bh   = (xcd << 2) | (slot & 3);        // 4 heads per XCD
    const int T    = 31 - (slot >> 2);               // longest first, global

    const size_t base  = (size_t)(bh >> 4) * SEQ * D_MODEL + (size_t)(bh & 15) * HEAD_DIM;
    const __bf16* kbase  = K + base;
    const __bf16* vtbase = Vt + (size_t)bh * HEAD_DIM * SEQ;

    __shared__ __bf16 Ks[2][64][72];    // [buf][key][dim]
    __shared__ __bf16 Vs[2][64][72];    // [buf][dim][key]
    __shared__ __bf16 P[4][16][72];     // per-wave [query l16][key 0..63]

    constexpr float C2 = 0.18033688011112042f;   // 0.125 * log2(e)
    const int sr = tid >> 2;            // staging row 0..63
    const int sc = (tid & 3) * 16;      // staging col 0,16,32,48

    const int Q0  = T * 64;
    const int q0w = Q0 + wave * 16;
    const int qg  = q0w + l16;

    const __bf16* qrow = Q + base + (size_t)(q0w + l16) * D_MODEL + quad * 8;
    const bf16x8 qf0 = *(const bf16x8*)(qrow);
    const bf16x8 qf1 = *(const bf16x8*)(qrow + 32);

    float mm = -__builtin_inff(), l_i = 0.f;
    floatx4 o0 = {}, o1 = {}, o2 = {}, o3 = {};

    // ---- prologue: tile 0 -> regs -> buf0 ----
    bf16x8 kr0, kr1, vr0, vr1;
    {
        const __bf16* kgp = kbase + (size_t)sr * D_MODEL + sc;
        kr0 = *(const bf16x8*)(kgp);
        kr1 = *(const bf16x8*)(kgp + 8);
        const __bf16* vgp = vtbase + (size_t)sr * SEQ + sc;
        vr0 = *(const bf16x8*)(vgp);
        vr1 = *(const bf16x8*)(vgp + 8);
    }
    __syncthreads();
    *(bf16x8*)&Ks[0][sr][sc]     = kr0;
    *(bf16x8*)&Ks[0][sr][sc + 8] = kr1;
    *(bf16x8*)&Vs[0][sr][sc]     = vr0;
    *(bf16x8*)&Vs[0][sr][sc + 8] = vr1;
    int cur = 0;

    for (int k0 = 0; k0 <= Q0; k0 += 64) {
        const bool pf = (k0 + 64 <= Q0);
        if (pf) {   // T14 issue-early: next-tile loads into regs
            const __bf16* kgp = kbase + (size_t)(k0 + 64 + sr) * D_MODEL + sc;
            kr0 = *(const bf16x8*)(kgp);
            kr1 = *(const bf16x8*)(kgp + 8);
            const __bf16* vgp = vtbase + (size_t)sr * SEQ + (k0 + 64) + sc;
            vr0 = *(const bf16x8*)(vgp);
            vr1 = *(const bf16x8*)(vgp + 8);
        }
        __syncthreads();   // buf[cur] writes visible; prev reads done

        // ---- scores: S^T[64 keys][16 queries], A = K rows from LDS ----
        floatx4 s0 = {}, s1 = {}, s2 = {}, s3 = {};
        __builtin_amdgcn_s_setprio(1);
        s0 = MFMA16(*(const bf16x8*)&Ks[cur][l16][quad * 8],      qf0, s0);
        s0 = MFMA16(*(const bf16x8*)&Ks[cur][l16][32 + quad * 8], qf1, s0);
        s1 = MFMA16(*(const bf16x8*)&Ks[cur][16 + l16][quad * 8],      qf0, s1);
        s1 = MFMA16(*(const bf16x8*)&Ks[cur][16 + l16][32 + quad * 8], qf1, s1);
        s2 = MFMA16(*(const bf16x8*)&Ks[cur][32 + l16][quad * 8],      qf0, s2);
        s2 = MFMA16(*(const bf16x8*)&Ks[cur][32 + l16][32 + quad * 8], qf1, s2);
        s3 = MFMA16(*(const bf16x8*)&Ks[cur][48 + l16][quad * 8],      qf0, s3);
        s3 = MFMA16(*(const bf16x8*)&Ks[cur][48 + l16][32 + quad * 8], qf1, s3);
        __builtin_amdgcn_s_setprio(0);

        if (k0 == Q0) {   // single masked tail block
#pragma unroll
            for (int r = 0; r < 4; ++r) {
                const int kb = k0 + quad * 4 + r;
                if (kb      > qg) s0[r] = -__builtin_inff();
                if (kb + 16 > qg) s1[r] = -__builtin_inff();
                if (kb + 32 > qg) s2[r] = -__builtin_inff();
                if (kb + 48 > qg) s3[r] = -__builtin_inff();
            }
        }

        // ---- online softmax over 64 keys (per-lane scalar state) ----
        // max3-shaped tree: 8 fusable v_max3, depth 3
        float ma = fmaxf(fmaxf(s0[0], s0[1]), s0[2]);
        float mb = fmaxf(fmaxf(s0[3], s1[0]), s1[1]);
        float mc = fmaxf(fmaxf(s1[2], s1[3]), s2[0]);
        float md = fmaxf(fmaxf(s2[1], s2[2]), s2[3]);
        float me = fmaxf(fmaxf(s3[0], s3[1]), s3[2]);
        ma = fmaxf(fmaxf(ma, mb), mc);
        md = fmaxf(fmaxf(md, me), s3[3]);
        float mx = fmaxf(ma, md);
        mx = fmaxf(mx, __shfl_xor(mx, 16));
        mx = fmaxf(mx, __shfl_xor(mx, 32));
        const float mxs = mx * C2;     // full row max, log2 domain

        // T13 defer-max: only rescale when the running max actually grows
        if (!__all(mxs - mm <= 8.0f)) {
            const float mmn   = fmaxf(mm, mxs);
            const float alpha = exp2f(mm - mmn);   // 0 on first iteration
            l_i *= alpha;
            o0 *= alpha; o1 *= alpha; o2 *= alpha; o3 *= alpha;
            mm = mmn;
        }

        float rs = 0.f;
#pragma unroll
        for (int r = 0; r < 4; ++r) {
            s0[r] = exp2f(s0[r] * C2 - mm);
            s1[r] = exp2f(s1[r] * C2 - mm);
            s2[r] = exp2f(s2[r] * C2 - mm);
            s3[r] = exp2f(s3[r] * C2 - mm);
            rs += s0[r] + s1[r] + s2[r] + s3[r];
        }
        rs += __shfl_xor(rs, 16);
        rs += __shfl_xor(rs, 32);
        l_i += rs;

        // ---- write-late staging: regs -> buf[cur^1] (no reader now) ----
        if (pf) {
            *(bf16x8*)&Ks[cur ^ 1][sr][sc]     = kr0;
            *(bf16x8*)&Ks[cur ^ 1][sr][sc + 8] = kr1;
            *(bf16x8*)&Vs[cur ^ 1][sr][sc]     = vr0;
            *(bf16x8*)&Vs[cur ^ 1][sr][sc + 8] = vr1;
        }

        // ---- P: C-layout -> per-wave LDS -> A-layout ----
        bf16x4 pw0, pw1, pw2, pw3;
#pragma unroll
        for (int r = 0; r < 4; ++r) {
            pw0[r] = (__bf16)s0[r]; pw1[r] = (__bf16)s1[r];
            pw2[r] = (__bf16)s2[r]; pw3[r] = (__bf16)s3[r];
        }
        *(bf16x4*)&P[wave][l16][quad * 4]      = pw0;
        *(bf16x4*)&P[wave][l16][16 + quad * 4] = pw1;
        *(bf16x4*)&P[wave][l16][32 + quad * 4] = pw2;
        *(bf16x4*)&P[wave][l16][48 + quad * 4] = pw3;
        const bf16x8 pp0 = *(const bf16x8*)&P[wave][l16][quad * 8];
        const bf16x8 pp1 = *(const bf16x8*)&P[wave][l16][32 + quad * 8];

        // ---- PV: O^T[dim][16q], A = V rows from LDS ----
        __builtin_amdgcn_s_setprio(1);
        o0 = MFMA16(*(const bf16x8*)&Vs[cur][l16][quad * 8],      pp0, o0);
        o0 = MFMA16(*(const bf16x8*)&Vs[cur][l16][32 + quad * 8], pp1, o0);
        o1 = MFMA16(*(const bf16x8*)&Vs[cur][16 + l16][quad * 8],      pp0, o1);
        o1 = MFMA16(*(const bf16x8*)&Vs[cur][16 + l16][32 + quad * 8], pp1, o1);
        o2 = MFMA16(*(const bf16x8*)&Vs[cur][32 + l16][quad * 8],      pp0, o2);
        o2 = MFMA16(*(const bf16x8*)&Vs[cur][32 + l16][32 + quad * 8], pp1, o2);
        o3 = MFMA16(*(const bf16x8*)&Vs[cur][48 + l16][quad * 8],      pp0, o3);
        o3 = MFMA16(*(const bf16x8*)&Vs[cur][48 + l16][32 + quad * 8], pp1, o3);
        __builtin_amdgcn_s_setprio(0);
        cur ^= 1;
    }

    // ---- epilogue: O[token q0w+l16][dim quad*4+r + 16g], bf16x4 ----
    const float rl = 1.0f / l_i;
    __bf16* orow = O + base + (size_t)(q0w + l16) * D_MODEL + quad * 4;
    bf16x4 w0, w1, w2, w3;
#pragma unroll
    for (int r = 0; r < 4; ++r) {
        w0[r] = (__bf16)(o0[r] * rl);
        w1[r] = (__bf16)(o1[r] * rl);
        w2[r] = (__bf16)(o2[r] * rl);
        w3[r] = (__bf16)(o3[r] * rl);
    }
    *(bf16x4*)(orow)      = w0;
    *(bf16x4*)(orow + 16) = w1;
    *(bf16x4*)(orow + 32) = w2;
    *(bf16x4*)(orow + 48) = w3;
}

// ---------------------------------------------------------------------------
// ws layout (40 MB): Xb 8 | Wb (Wq,Wk,Wv,Wo cat) 8 | Qb 8 | Kb 8 | Vt 8.
// RoPE table (512 KB) lives in d_out: written by convert_all, read by
// gemm_tiled<0>, dead by the time gemm_tiled<1> overwrites d_out.
// Attention output in-place over Qb. Inputs fp32, output fp32.
// ---------------------------------------------------------------------------
extern "C" void kernel_launch(void* const* d_in, const int* in_sizes, int n_in,
                              void* d_out, int out_size, void* d_ws, size_t ws_size,
                              hipStream_t stream) {
    const int* pos = (const int*)d_in[1];
    float* out = (float*)d_out;

    const size_t xe = (size_t)M_TOK * D_MODEL;      // 4M elements
    const size_t we = (size_t)D_MODEL * D_MODEL;    // 1M elements
    __bf16* Xb = (__bf16*)d_ws;
    __bf16* Wb = Xb + xe;          // [Wq | Wk | Wv | Wo]
    __bf16* Qb = Wb + 4 * we;
    __bf16* Kb = Qb + xe;
    __bf16* Vt = Kb + xe;          // [b*16+h][64][2048] transposed V
    float2* rt = (float2*)d_out;   // RoPE table, scratch use of out buffer

    convert_all<<<4096, 256, 0, stream>>>(
        (const float*)d_in[0], (const float*)d_in[2], (const float*)d_in[3],
        (const float*)d_in[4], (const float*)d_in[5], Xb, pos, rt);

    gemm_tiled<0><<<dim3(M_TOK / 128, 3072 / 128), 256, 0, stream>>>(
        Xb, Wb, Qb, Kb, Vt, nullptr, rt);

    // unpaired, XCD-clustered GLOBAL-LPT grid: 1024 blocks, 3 resident/CU
    attn_fused<<<dim3(32, 32), 256, 0, stream>>>(Qb, Kb, Vt, Qb);

    gemm_tiled<1><<<dim3(M_TOK / 128, D_MODEL / 128), 256, 0, stream>>>(
        Qb, Wb + 3 * we, nullptr, nullptr, nullptr, out, rt);
}